// Round 1
// baseline (137.905 us; speedup 1.0000x reference)
//
#include <hip/hip_runtime.h>
#include <hip/hip_bf16.h>
#include <cstdint>

// Shapes are fixed by the reference: B=4, T=2048, D=512, H=8, hd=64, MAX_RADIUS=16.
#define T_LEN 2048
#define B_SZ 4
#define D_MOD 512
#define N_HEAD 8
#define HDIM 64
#define QKV_N 1536
#define M_ROWS 8192   // B*T

typedef uint32_t u32;
typedef uint16_t u16;
typedef __attribute__((ext_vector_type(8))) __bf16 bf16x8;
typedef __attribute__((ext_vector_type(4))) float f32x4;

__device__ __forceinline__ u16 f2bf(float f) {
    u32 u = __builtin_bit_cast(u32, f);
    u32 r = (u + 0x7FFFu + ((u >> 16) & 1u)) >> 16;   // RNE
    return (u16)r;
}
__device__ __forceinline__ float bf2f(u16 h) {
    u32 u = ((u32)h) << 16;
    return __builtin_bit_cast(float, u);
}

// ---------------- cast f32 -> bf16, 8 elems/thread, fully coalesced ----------------
__global__ void cast_kernel(const float* __restrict__ in, u16* __restrict__ out, int n) {
    int i = (blockIdx.x * blockDim.x + threadIdx.x) * 8;
    if (i >= n) return;
    const float4* p = (const float4*)(in + i);
    float4 a = p[0], b = p[1];
    u32 r0 = (u32)f2bf(a.x) | ((u32)f2bf(a.y) << 16);
    u32 r1 = (u32)f2bf(a.z) | ((u32)f2bf(a.w) << 16);
    u32 r2 = (u32)f2bf(b.x) | ((u32)f2bf(b.y) << 16);
    u32 r3 = (u32)f2bf(b.z) | ((u32)f2bf(b.w) << 16);
    *(uint4*)(out + i) = make_uint4(r0, r1, r2, r3);
}

// ---------------- GEMM: C[M,N] = A[M,K] * B[N,K]^T + bias, bf16 in, m97 structure ----------------
// 128x128 tile, BK=32, 256 threads (2x2 waves of 64x64 = 4x4 MFMA 16x16x32 each).
// global_load_lds width=16; LDS 16B-chunks XOR-swizzled by (row&3) to spread banks.
#define BM 128
#define BN 128
#define BK 32

template <bool OUT_BF16>
__global__ __launch_bounds__(256, 2)
void gemm_bt(const u16* __restrict__ A, const u16* __restrict__ B,
             const float* __restrict__ bias, void* __restrict__ C,
             int M, int N, int K)
{
    __shared__ u16 lda[BM * BK];
    __shared__ u16 ldb[BN * BK];
    const int tid  = threadIdx.x;
    const int wave = tid >> 6;
    const int lane = tid & 63;
    const int bn = blockIdx.x, bm = blockIdx.y;
    const int wm = wave >> 1, wn = wave & 1;

    f32x4 acc[4][4] = {};

    // staging: lane l -> lds 16B chunk l within the wave's 16-row group (global_load_lds constraint);
    // global chunk is XOR-swizzled so fragment reads spread across banks
    const int srow = lane >> 2;                 // 0..15 row within group
    const int sg   = (lane & 3) ^ (srow & 3);   // swizzled global 8-elem chunk
    const long a_base = (long)bm * BM;
    const long b_base = (long)bn * BN;

    // fragment offsets: A[m=lane&15][k=quad*8+j] (m89-verified layout)
    const int fr = lane & 15;
    const int fq = lane >> 4;
    int a_off[4], b_off[4];
#pragma unroll
    for (int i = 0; i < 4; ++i) {
        int ra = wm * 64 + i * 16 + fr;
        a_off[i] = ra * BK + ((fq ^ (ra & 3)) * 8);
        int rb = wn * 64 + i * 16 + fr;
        b_off[i] = rb * BK + ((fq ^ (rb & 3)) * 8);
    }

    for (int kk = 0; kk < K; kk += BK) {
#pragma unroll
        for (int c = 0; c < 2; ++c) {
            int r = wave * 32 + c * 16 + srow;
            const u16* ga = A + (a_base + r) * (long)K + kk + sg * 8;
            __builtin_amdgcn_global_load_lds(
                (const __attribute__((address_space(1))) void*)ga,
                (__attribute__((address_space(3))) void*)&lda[(wave * 32 + c * 16) * BK],
                16, 0, 0);
            const u16* gb = B + (b_base + r) * (long)K + kk + sg * 8;
            __builtin_amdgcn_global_load_lds(
                (const __attribute__((address_space(1))) void*)gb,
                (__attribute__((address_space(3))) void*)&ldb[(wave * 32 + c * 16) * BK],
                16, 0, 0);
        }
        __syncthreads();
        bf16x8 af[4], bfr[4];
#pragma unroll
        for (int i = 0; i < 4; ++i) af[i]  = *(const bf16x8*)&lda[a_off[i]];
#pragma unroll
        for (int i = 0; i < 4; ++i) bfr[i] = *(const bf16x8*)&ldb[b_off[i]];
#pragma unroll
        for (int mi = 0; mi < 4; ++mi)
#pragma unroll
            for (int ni = 0; ni < 4; ++ni)
                acc[mi][ni] = __builtin_amdgcn_mfma_f32_16x16x32_bf16(
                    af[mi], bfr[ni], acc[mi][ni], 0, 0, 0);
        __syncthreads();
    }

    // epilogue: C/D layout col=lane&15, row=(lane>>4)*4+reg (m89-verified)
    const long row0 = a_base + wm * 64;
    const long col0 = b_base + wn * 64;
#pragma unroll
    for (int mi = 0; mi < 4; ++mi) {
#pragma unroll
        for (int ni = 0; ni < 4; ++ni) {
            long col = col0 + ni * 16 + fr;
            float bv = bias[col];
            long rowb = row0 + mi * 16 + fq * 4;
#pragma unroll
            for (int rr = 0; rr < 4; ++rr) {
                float v = acc[mi][ni][rr] + bv;
                long idx = (rowb + rr) * (long)N + col;
                if (OUT_BF16) ((u16*)C)[idx] = f2bf(v);
                else          ((float*)C)[idx] = v;
            }
        }
    }
}

// ---------------- banded attention ----------------
// One block = (b, h, 64-query chunk). 256 threads: 4 lanes per query, 16 dims each.
// K/V window [q0-16, q0+80) staged in LDS, row stride 66 elems (132B = 33 dwords ->
// consecutive rows shift 1 bank; <=2 lanes/bank = free). Online softmax (no dynamic
// register indexing). Window w uniform per block -> no wave divergence except seq edges.
#define AQ 64
#define AW 16
#define AROWS 96      // AQ + 2*AW
#define ASTR 66

__global__ __launch_bounds__(256)
void attn_kernel(const u16* __restrict__ qkv, const float* __restrict__ radius,
                 u16* __restrict__ out)
{
    __shared__ u16 ks[AROWS * ASTR];
    __shared__ u16 vs[AROWS * ASTR];

    const int tid = threadIdx.x;
    const int bid = blockIdx.x;
    const int qc = bid & 31;
    const int h  = (bid >> 5) & 7;
    const int b  = bid >> 8;
    const int q0 = qc * AQ;

    // per-head window: r = max(sigmoid(rad)*16, 1); integer rel <= r  <=>  rel <= floor(r)
    float rad = radius[h];
    float r = 16.0f / (1.0f + __expf(-rad));
    r = fmaxf(r, 1.0f);
    const int w = (int)floorf(r);

    // stage K and V windows (clamped rows; clamped values are masked out later)
    for (int cid = tid; cid < AROWS * 8; cid += 256) {
        int row = cid >> 3;
        int ch  = cid & 7;
        int t = q0 - AW + row;
        t = min(max(t, 0), T_LEN - 1);
        const u16* gk = qkv + ((long)(b * T_LEN + t)) * QKV_N + D_MOD + h * HDIM + ch * 8;
        const u16* gv = gk + D_MOD;
        uint4 kv4 = *(const uint4*)gk;
        uint4 vv4 = *(const uint4*)gv;
        u32* kd = (u32*)&ks[row * ASTR + ch * 8];
        u32* vd = (u32*)&vs[row * ASTR + ch * 8];
        kd[0] = kv4.x; kd[1] = kv4.y; kd[2] = kv4.z; kd[3] = kv4.w;
        vd[0] = vv4.x; vd[1] = vv4.y; vd[2] = vv4.z; vd[3] = vv4.w;
    }

    const int qi = tid >> 2;
    const int g  = tid & 3;
    const int q  = q0 + qi;
    const long qrow = (long)(b * T_LEN + q);

    // load this query's 16 dims, pre-scaled by 1/sqrt(hd)
    float qreg[16];
    {
        const u16* gq = qkv + qrow * QKV_N + h * HDIM + g * 16;
        uint4 q1 = *(const uint4*)gq;
        uint4 q2 = *(const uint4*)(gq + 8);
        u32 ww[8] = {q1.x, q1.y, q1.z, q1.w, q2.x, q2.y, q2.z, q2.w};
#pragma unroll
        for (int j = 0; j < 8; ++j) {
            qreg[2 * j]     = bf2f((u16)(ww[j] & 0xffffu)) * 0.125f;
            qreg[2 * j + 1] = bf2f((u16)(ww[j] >> 16))     * 0.125f;
        }
    }
    __syncthreads();

    float m = -1e30f, l = 0.0f;
    float acc[16];
#pragma unroll
    for (int d = 0; d < 16; ++d) acc[d] = 0.0f;

    const int colbase = g * 16;
    for (int rel = -w; rel <= w; ++rel) {
        int j = q + rel;
        if (j < 0 || j >= T_LEN) continue;   // same decision across the 4-lane group
        int row = qi + AW + rel;
        const u32* kr = (const u32*)&ks[row * ASTR + colbase];
        float s = 0.0f;
#pragma unroll
        for (int dd = 0; dd < 8; ++dd) {
            u32 wv = kr[dd];
            s += qreg[2 * dd]     * bf2f((u16)(wv & 0xffffu));
            s += qreg[2 * dd + 1] * bf2f((u16)(wv >> 16));
        }
        s += __shfl_xor(s, 1);
        s += __shfl_xor(s, 2);
        float mn = fmaxf(m, s);
        float sc = __expf(m - mn);
        float p  = __expf(s - mn);
        m = mn;
        l = l * sc + p;
        const u32* vr = (const u32*)&vs[row * ASTR + colbase];
#pragma unroll
        for (int dd = 0; dd < 8; ++dd) {
            u32 wv = vr[dd];
            acc[2 * dd]     = acc[2 * dd]     * sc + p * bf2f((u16)(wv & 0xffffu));
            acc[2 * dd + 1] = acc[2 * dd + 1] * sc + p * bf2f((u16)(wv >> 16));
        }
    }

    float inv = 1.0f / l;   // l >= 1 term always (rel=0 in band)
    u32 o[8];
#pragma unroll
    for (int j2 = 0; j2 < 8; ++j2) {
        u16 lo = f2bf(acc[2 * j2] * inv);
        u16 hi = f2bf(acc[2 * j2 + 1] * inv);
        o[j2] = (u32)lo | ((u32)hi << 16);
    }
    u16* po = out + qrow * D_MOD + h * HDIM + colbase;
    *(uint4*)po       = make_uint4(o[0], o[1], o[2], o[3]);
    *(uint4*)(po + 8) = make_uint4(o[4], o[5], o[6], o[7]);
}

// ---------------- launch ----------------
extern "C" void kernel_launch(void* const* d_in, const int* in_sizes, int n_in,
                              void* d_out, int out_size, void* d_ws, size_t ws_size,
                              hipStream_t stream)
{
    (void)in_sizes; (void)n_in; (void)out_size; (void)ws_size;
    const float* x      = (const float*)d_in[0];
    const float* radius = (const float*)d_in[1];
    const float* w_in   = (const float*)d_in[2];
    const float* b_in   = (const float*)d_in[3];
    const float* w_out  = (const float*)d_in[4];
    const float* b_out  = (const float*)d_in[5];
    float* outp = (float*)d_out;

    // workspace carve (all 16B-aligned sizes): total ~44 MB
    char* ws = (char*)d_ws;
    u16* x_bf    = (u16*)ws;  ws += (size_t)M_ROWS * D_MOD * 2;      // 8 MB
    u16* win_bf  = (u16*)ws;  ws += (size_t)QKV_N * D_MOD * 2;       // 1.5 MB
    u16* wout_bf = (u16*)ws;  ws += (size_t)D_MOD * D_MOD * 2;       // 0.5 MB
    u16* qkv_bf  = (u16*)ws;  ws += (size_t)M_ROWS * QKV_N * 2;      // 25 MB
    u16* attn_bf = (u16*)ws;                                         // 8 MB

    cast_kernel<<<(M_ROWS * D_MOD) / 2048, 256, 0, stream>>>(x, x_bf, M_ROWS * D_MOD);
    cast_kernel<<<(QKV_N * D_MOD) / 2048, 256, 0, stream>>>(w_in, win_bf, QKV_N * D_MOD);
    cast_kernel<<<(D_MOD * D_MOD) / 2048, 256, 0, stream>>>(w_out, wout_bf, D_MOD * D_MOD);

    gemm_bt<true ><<<dim3(QKV_N / BN, M_ROWS / BM), 256, 0, stream>>>(
        x_bf, win_bf, b_in, qkv_bf, M_ROWS, QKV_N, D_MOD);
    attn_kernel<<<B_SZ * N_HEAD * (T_LEN / AQ), 256, 0, stream>>>(qkv_bf, radius, attn_bf);
    gemm_bt<false><<<dim3(D_MOD / BN, M_ROWS / BM), 256, 0, stream>>>(
        attn_bf, wout_bf, b_out, outp, M_ROWS, D_MOD, D_MOD);
}

// Round 2
// 130.449 us; speedup vs baseline: 1.0572x; 1.0572x over previous
//
#include <hip/hip_runtime.h>
#include <hip/hip_bf16.h>
#include <cstdint>

// Shapes fixed by the reference: B=4, T=2048, D=512, H=8, hd=64, MAX_RADIUS=16.
#define T_LEN 2048
#define B_SZ 4
#define D_MOD 512
#define N_HEAD 8
#define HDIM 64
#define QKV_N 1536
#define M_ROWS 8192   // B*T

typedef uint32_t u32;
typedef uint16_t u16;
typedef __attribute__((ext_vector_type(8))) __bf16 bf16x8;
typedef __attribute__((ext_vector_type(4))) float f32x4;

__device__ __forceinline__ u16 f2bf(float f) {
    u32 u = __builtin_bit_cast(u32, f);
    u32 r = (u + 0x7FFFu + ((u >> 16) & 1u)) >> 16;   // RNE
    return (u16)r;
}
__device__ __forceinline__ float bf2f(u16 h) {
    u32 u = ((u32)h) << 16;
    return __builtin_bit_cast(float, u);
}

// ---------------- fused cast f32 -> bf16 for all three inputs ----------------
// Segment boundaries are multiples of 2048 => block-uniform branch, 8 elems/thread.
__global__ void cast3_kernel(const float* __restrict__ a, int na,
                             const float* __restrict__ b, int nb,
                             const float* __restrict__ c,
                             u16* __restrict__ oa, u16* __restrict__ ob, u16* __restrict__ oc) {
    int i8 = (blockIdx.x * blockDim.x + threadIdx.x) * 8;
    const float* src; u16* dst; int off;
    if (i8 < na)           { src = a; dst = oa; off = i8; }
    else if (i8 < na + nb) { src = b; dst = ob; off = i8 - na; }
    else                   { src = c; dst = oc; off = i8 - na - nb; }
    const float4* p = (const float4*)(src + off);
    float4 x = p[0], y = p[1];
    u32 r0 = (u32)f2bf(x.x) | ((u32)f2bf(x.y) << 16);
    u32 r1 = (u32)f2bf(x.z) | ((u32)f2bf(x.w) << 16);
    u32 r2 = (u32)f2bf(y.x) | ((u32)f2bf(y.y) << 16);
    u32 r3 = (u32)f2bf(y.z) | ((u32)f2bf(y.w) << 16);
    *(uint4*)(dst + off) = make_uint4(r0, r1, r2, r3);
}

// ---------------- GEMM: C[M,N] = A[M,K] * B[N,K]^T + bias, bf16 in ----------------
// BN=128 fixed; BMt in {128, 64}. BMt=128: waves 2x2, each 64x64 (4x4 MFMA).
// BMt=64: waves 2x2, each 32x64 (2x4 MFMA) -> 2x more blocks for small-N GEMMs.
#define BK 32

template <bool OUT_BF16, int BMt>
__global__ __launch_bounds__(256, 2)
void gemm_bt(const u16* __restrict__ A, const u16* __restrict__ B,
             const float* __restrict__ bias, void* __restrict__ C,
             int M, int N, int K)
{
    constexpr int WM = BMt / 2;     // wave tile rows
    constexpr int MI = WM / 16;     // acc tiles along M per wave
    __shared__ u16 lda[BMt * BK];
    __shared__ u16 ldb[128 * BK];
    const int tid  = threadIdx.x;
    const int wave = tid >> 6;
    const int lane = tid & 63;
    const int bn = blockIdx.x, bm = blockIdx.y;
    const int wm = wave >> 1, wn = wave & 1;

    f32x4 acc[MI][4] = {};

    // staging: lane l -> 16B chunk, global chunk XOR-swizzled by (row&3)
    const int srow = lane >> 2;
    const int sg   = (lane & 3) ^ (srow & 3);
    const long a_base = (long)bm * BMt;
    const long b_base = (long)bn * 128;

    const int fr = lane & 15;
    const int fq = lane >> 4;
    int a_off[MI], b_off[4];
#pragma unroll
    for (int i = 0; i < MI; ++i) {
        int ra = wm * WM + i * 16 + fr;
        a_off[i] = ra * BK + ((fq ^ (ra & 3)) * 8);
    }
#pragma unroll
    for (int i = 0; i < 4; ++i) {
        int rb = wn * 64 + i * 16 + fr;
        b_off[i] = rb * BK + ((fq ^ (rb & 3)) * 8);
    }

    for (int kk = 0; kk < K; kk += BK) {
#pragma unroll
        for (int c = 0; c < BMt / 64; ++c) {
            int r = wave * (BMt / 4) + c * 16 + srow;
            const u16* ga = A + (a_base + r) * (long)K + kk + sg * 8;
            __builtin_amdgcn_global_load_lds(
                (const __attribute__((address_space(1))) void*)ga,
                (__attribute__((address_space(3))) void*)&lda[(wave * (BMt / 4) + c * 16) * BK],
                16, 0, 0);
        }
#pragma unroll
        for (int c = 0; c < 2; ++c) {
            int r = wave * 32 + c * 16 + srow;
            const u16* gb = B + (b_base + r) * (long)K + kk + sg * 8;
            __builtin_amdgcn_global_load_lds(
                (const __attribute__((address_space(1))) void*)gb,
                (__attribute__((address_space(3))) void*)&ldb[(wave * 32 + c * 16) * BK],
                16, 0, 0);
        }
        __syncthreads();
        bf16x8 af[MI], bfr[4];
#pragma unroll
        for (int i = 0; i < MI; ++i) af[i]  = *(const bf16x8*)&lda[a_off[i]];
#pragma unroll
        for (int i = 0; i < 4; ++i) bfr[i] = *(const bf16x8*)&ldb[b_off[i]];
#pragma unroll
        for (int mi = 0; mi < MI; ++mi)
#pragma unroll
            for (int ni = 0; ni < 4; ++ni)
                acc[mi][ni] = __builtin_amdgcn_mfma_f32_16x16x32_bf16(
                    af[mi], bfr[ni], acc[mi][ni], 0, 0, 0);
        __syncthreads();
    }

    // epilogue: C/D layout col=lane&15, row=(lane>>4)*4+reg
    const long row0 = a_base + wm * WM;
    const long col0 = b_base + wn * 64;
#pragma unroll
    for (int mi = 0; mi < MI; ++mi) {
#pragma unroll
        for (int ni = 0; ni < 4; ++ni) {
            long col = col0 + ni * 16 + fr;
            float bv = bias[col];
            long rowb = row0 + mi * 16 + fq * 4;
#pragma unroll
            for (int rr = 0; rr < 4; ++rr) {
                float v = acc[mi][ni][rr] + bv;
                long idx = (rowb + rr) * (long)N + col;
                if (OUT_BF16) ((u16*)C)[idx] = f2bf(v);
                else          ((float*)C)[idx] = v;
            }
        }
    }
}

// ---------------- banded attention, query-pair version ----------------
// One block = (b, h, 128-query chunk). 256 threads: 4 lanes per QUERY-PAIR
// (queries 2p, 2p+1), 16 dims each. The pair shares one K/V row stream:
// 2w+2 rows per pair instead of 2*(2w+1) -> LDS read traffic halved.
// LDS layout: row stride ASTR=70 elems, 16-elem chunk g stored at g*18 elems.
// Read bank (dword) = 6p + 9g + d  -> exactly 2 lanes/bank = free (m136).
#define AQ 128
#define AW 16
#define AROWS (AQ + 2 * AW)   // 160
#define ASTR 70

__device__ __forceinline__ void unpack16(const u32* __restrict__ src, float* __restrict__ dst) {
#pragma unroll
    for (int dd = 0; dd < 8; ++dd) {
        u32 wv = src[dd];
        dst[2 * dd]     = bf2f((u16)(wv & 0xffffu));
        dst[2 * dd + 1] = bf2f((u16)(wv >> 16));
    }
}

__global__ __launch_bounds__(256)
void attn_kernel(const u16* __restrict__ qkv, const float* __restrict__ radius,
                 u16* __restrict__ out)
{
    __shared__ u16 ks[AROWS * ASTR];
    __shared__ u16 vs[AROWS * ASTR];

    const int tid = threadIdx.x;
    const int bid = blockIdx.x;
    const int qc = bid & 15;
    const int h  = (bid >> 4) & 7;
    const int b  = bid >> 7;
    const int q0 = qc * AQ;

    float rad = radius[h];
    float r = 16.0f / (1.0f + __expf(-rad));
    r = fmaxf(r, 1.0f);
    const int w = (int)floorf(r);       // 1..15

    // stage K/V window [q0-16, q0+143], rows clamped (clamped rows masked later)
    for (int cid = tid; cid < AROWS * 4; cid += 256) {
        int row = cid >> 2;
        int ch  = cid & 3;
        int t = min(max(q0 - AW + row, 0), T_LEN - 1);
        const u16* gk = qkv + ((long)(b * T_LEN + t)) * QKV_N + D_MOD + h * HDIM + ch * 16;
        const u16* gv = gk + D_MOD;
        uint4 k0 = *(const uint4*)gk, k1 = *(const uint4*)(gk + 8);
        uint4 v0 = *(const uint4*)gv, v1 = *(const uint4*)(gv + 8);
        u32* kd = (u32*)&ks[row * ASTR + ch * 18];
        u32* vd = (u32*)&vs[row * ASTR + ch * 18];
        kd[0] = k0.x; kd[1] = k0.y; kd[2] = k0.z; kd[3] = k0.w;
        kd[4] = k1.x; kd[5] = k1.y; kd[6] = k1.z; kd[7] = k1.w;
        vd[0] = v0.x; vd[1] = v0.y; vd[2] = v0.z; vd[3] = v0.w;
        vd[4] = v1.x; vd[5] = v1.y; vd[6] = v1.z; vd[7] = v1.w;
    }

    const int p = tid >> 2;          // pair index 0..63
    const int g = tid & 3;           // dim group (16 dims)
    const int qA = q0 + 2 * p;
    const int qB = qA + 1;
    const long rowA = (long)(b * T_LEN + qA);
    const long rowB = rowA + 1;

    // load both queries' 16 dims, pre-scaled by 1/sqrt(64)
    float qregA[16], qregB[16];
    {
        const u16* gq = qkv + rowA * QKV_N + h * HDIM + g * 16;
        u32 wa[8], wb[8];
        uint4 t0 = *(const uint4*)gq,              t1 = *(const uint4*)(gq + 8);
        uint4 t2 = *(const uint4*)(gq + QKV_N),    t3 = *(const uint4*)(gq + QKV_N + 8);
        wa[0]=t0.x; wa[1]=t0.y; wa[2]=t0.z; wa[3]=t0.w; wa[4]=t1.x; wa[5]=t1.y; wa[6]=t1.z; wa[7]=t1.w;
        wb[0]=t2.x; wb[1]=t2.y; wb[2]=t2.z; wb[3]=t2.w; wb[4]=t3.x; wb[5]=t3.y; wb[6]=t3.z; wb[7]=t3.w;
#pragma unroll
        for (int j = 0; j < 8; ++j) {
            qregA[2 * j]     = bf2f((u16)(wa[j] & 0xffffu)) * 0.125f;
            qregA[2 * j + 1] = bf2f((u16)(wa[j] >> 16))     * 0.125f;
            qregB[2 * j]     = bf2f((u16)(wb[j] & 0xffffu)) * 0.125f;
            qregB[2 * j + 1] = bf2f((u16)(wb[j] >> 16))     * 0.125f;
        }
    }
    __syncthreads();

    float mA = -1e30f, lA = 0.0f, mB = -1e30f, lB = 0.0f;
    float accA[16], accB[16];
#pragma unroll
    for (int d = 0; d < 16; ++d) { accA[d] = 0.0f; accB[d] = 0.0f; }

    const int imax = 2 * w + 1;
    for (int i = 0; i <= imax; ++i) {
        int jrow = 2 * p - w + i;        // key index relative to q0
        int j = q0 + jrow;               // global key index
        int row = jrow + AW;             // LDS row, in [0, 159]
        float kf[16];
        unpack16((const u32*)&ks[row * ASTR + g * 18], kf);
        float sA = 0.0f, sB = 0.0f;
#pragma unroll
        for (int d = 0; d < 16; ++d) { sA += qregA[d] * kf[d]; sB += qregB[d] * kf[d]; }
        sA += __shfl_xor(sA, 1); sA += __shfl_xor(sA, 2);
        sB += __shfl_xor(sB, 1); sB += __shfl_xor(sB, 2);
        bool inb = ((unsigned)j) < (unsigned)T_LEN;
        bool vA = inb && (i < imax);     // rel_A = i - w in [-w, w]
        bool vB = inb && (i > 0);        // rel_B = i - w - 1 in [-w, w]
        float mnA = fmaxf(mA, vA ? sA : -1e30f);
        float scA = __expf(mA - mnA);
        float pA  = vA ? __expf(sA - mnA) : 0.0f;
        mA = mnA; lA = lA * scA + pA;
        float mnB = fmaxf(mB, vB ? sB : -1e30f);
        float scB = __expf(mB - mnB);
        float pB  = vB ? __expf(sB - mnB) : 0.0f;
        mB = mnB; lB = lB * scB + pB;
        float vf[16];
        unpack16((const u32*)&vs[row * ASTR + g * 18], vf);
#pragma unroll
        for (int d = 0; d < 16; ++d) {
            accA[d] = accA[d] * scA + pA * vf[d];
            accB[d] = accB[d] * scB + pB * vf[d];
        }
    }

    float invA = 1.0f / lA;   // rel=0 always in band -> l >= ~1
    float invB = 1.0f / lB;
    u32 oA[8], oB[8];
#pragma unroll
    for (int j2 = 0; j2 < 8; ++j2) {
        oA[j2] = (u32)f2bf(accA[2 * j2] * invA) | ((u32)f2bf(accA[2 * j2 + 1] * invA) << 16);
        oB[j2] = (u32)f2bf(accB[2 * j2] * invB) | ((u32)f2bf(accB[2 * j2 + 1] * invB) << 16);
    }
    u16* poA = out + rowA * D_MOD + h * HDIM + g * 16;
    u16* poB = out + rowB * D_MOD + h * HDIM + g * 16;
    *(uint4*)poA       = make_uint4(oA[0], oA[1], oA[2], oA[3]);
    *(uint4*)(poA + 8) = make_uint4(oA[4], oA[5], oA[6], oA[7]);
    *(uint4*)poB       = make_uint4(oB[0], oB[1], oB[2], oB[3]);
    *(uint4*)(poB + 8) = make_uint4(oB[4], oB[5], oB[6], oB[7]);
}

// ---------------- launch ----------------
extern "C" void kernel_launch(void* const* d_in, const int* in_sizes, int n_in,
                              void* d_out, int out_size, void* d_ws, size_t ws_size,
                              hipStream_t stream)
{
    (void)in_sizes; (void)n_in; (void)out_size; (void)ws_size;
    const float* x      = (const float*)d_in[0];
    const float* radius = (const float*)d_in[1];
    const float* w_in   = (const float*)d_in[2];
    const float* b_in   = (const float*)d_in[3];
    const float* w_out  = (const float*)d_in[4];
    const float* b_out  = (const float*)d_in[5];
    float* outp = (float*)d_out;

    char* ws = (char*)d_ws;
    u16* x_bf    = (u16*)ws;  ws += (size_t)M_ROWS * D_MOD * 2;
    u16* win_bf  = (u16*)ws;  ws += (size_t)QKV_N * D_MOD * 2;
    u16* wout_bf = (u16*)ws;  ws += (size_t)D_MOD * D_MOD * 2;
    u16* qkv_bf  = (u16*)ws;  ws += (size_t)M_ROWS * QKV_N * 2;
    u16* attn_bf = (u16*)ws;

    const int na = M_ROWS * D_MOD;        // 4194304
    const int nb = QKV_N * D_MOD;         // 786432
    const int nc = D_MOD * D_MOD;         // 262144
    cast3_kernel<<<(na + nb + nc) / 2048, 256, 0, stream>>>(
        x, na, w_in, nb, w_out, x_bf, win_bf, wout_bf);

    gemm_bt<true, 128><<<dim3(QKV_N / 128, M_ROWS / 128), 256, 0, stream>>>(
        x_bf, win_bf, b_in, qkv_bf, M_ROWS, QKV_N, D_MOD);
    attn_kernel<<<B_SZ * N_HEAD * (T_LEN / AQ), 256, 0, stream>>>(qkv_bf, radius, attn_bf);
    gemm_bt<false, 64><<<dim3(D_MOD / 128, M_ROWS / 64), 256, 0, stream>>>(
        attn_bf, wout_bf, b_out, outp, M_ROWS, D_MOD, D_MOD);
}

// Round 3
// 128.199 us; speedup vs baseline: 1.0757x; 1.0175x over previous
//
#include <hip/hip_runtime.h>
#include <hip/hip_bf16.h>
#include <cstdint>

// Shapes fixed by the reference: B=4, T=2048, D=512, H=8, hd=64, MAX_RADIUS=16.
#define T_LEN 2048
#define B_SZ 4
#define D_MOD 512
#define N_HEAD 8
#define HDIM 64
#define QKV_N 1536
#define M_ROWS 8192   // B*T

typedef uint32_t u32;
typedef uint16_t u16;
typedef __attribute__((ext_vector_type(8))) __bf16 bf16x8;
typedef __attribute__((ext_vector_type(4))) float f32x4;

__device__ __forceinline__ u16 f2bf(float f) {
    u32 u = __builtin_bit_cast(u32, f);
    u32 r = (u + 0x7FFFu + ((u >> 16) & 1u)) >> 16;   // RNE
    return (u16)r;
}
__device__ __forceinline__ float bf2f(u16 h) {
    u32 u = ((u32)h) << 16;
    return __builtin_bit_cast(float, u);
}

// ---------------- fused cast f32 -> bf16 for all three inputs ----------------
__global__ void cast3_kernel(const float* __restrict__ a, int na,
                             const float* __restrict__ b, int nb,
                             const float* __restrict__ c,
                             u16* __restrict__ oa, u16* __restrict__ ob, u16* __restrict__ oc) {
    int i8 = (blockIdx.x * blockDim.x + threadIdx.x) * 8;
    const float* src; u16* dst; int off;
    if (i8 < na)           { src = a; dst = oa; off = i8; }
    else if (i8 < na + nb) { src = b; dst = ob; off = i8 - na; }
    else                   { src = c; dst = oc; off = i8 - na - nb; }
    const float4* p = (const float4*)(src + off);
    float4 x = p[0], y = p[1];
    u32 r0 = (u32)f2bf(x.x) | ((u32)f2bf(x.y) << 16);
    u32 r1 = (u32)f2bf(x.z) | ((u32)f2bf(x.w) << 16);
    u32 r2 = (u32)f2bf(y.x) | ((u32)f2bf(y.y) << 16);
    u32 r3 = (u32)f2bf(y.z) | ((u32)f2bf(y.w) << 16);
    *(uint4*)(dst + off) = make_uint4(r0, r1, r2, r3);
}

// ---------------- GEMM: C[M,N] = A[M,K] * B[N,K]^T + bias, bf16 in ----------------
// BK=64: half the barriers of the m97 BK=32 structure -> 32 MFMA per wave per
// barrier pair (short-K amortization). LDS 32 KB/block keeps ~3 blocks/CU.
// Staging: lane l stages 16B chunk (l&7)^(l>>3) of its 8-row group (global_load_lds
// is uniform-base + lane*16). Fragment chunk = (kh*4+fq)^(row&7) -> 2-way banks = free.
#define BK 64

template <bool OUT_BF16, int BMt>
__global__ __launch_bounds__(256, 2)
void gemm_bt(const u16* __restrict__ A, const u16* __restrict__ B,
             const float* __restrict__ bias, void* __restrict__ C,
             int M, int N, int K)
{
    constexpr int WM = BMt / 2;     // wave tile rows
    constexpr int MI = WM / 16;     // acc tiles along M per wave
    __shared__ alignas(16) u16 lda[BMt * BK];
    __shared__ alignas(16) u16 ldb[128 * BK];
    const int tid  = threadIdx.x;
    const int wave = tid >> 6;
    const int lane = tid & 63;
    const int bn = blockIdx.x, bm = blockIdx.y;
    const int wm = wave >> 1, wn = wave & 1;

    f32x4 acc[MI][4] = {};

    // staging decomposition: lane -> (row-in-8-group, chunk), chunk XOR-swizzled
    const int srow8 = lane >> 3;               // 0..7 row within 8-row group
    const int sg    = (lane & 7) ^ srow8;      // swizzled global 8-elem chunk
    const long a_base = (long)bm * BMt;
    const long b_base = (long)bn * 128;

    const int fr = lane & 15;
    const int fq = lane >> 4;
    int a_off[MI], b_off[4];
#pragma unroll
    for (int i = 0; i < MI; ++i) {
        int ra = wm * WM + i * 16 + fr;
        a_off[i] = ra * BK + ((fq ^ (ra & 7)) * 8);
    }
#pragma unroll
    for (int i = 0; i < 4; ++i) {
        int rb = wn * 64 + i * 16 + fr;
        b_off[i] = rb * BK + ((fq ^ (rb & 7)) * 8);
    }

    for (int kk = 0; kk < K; kk += BK) {
#pragma unroll
        for (int j = 0; j < BMt / 32; ++j) {
            int r = wave * (BMt / 4) + j * 8 + srow8;
            const u16* ga = A + (a_base + r) * (long)K + kk + sg * 8;
            __builtin_amdgcn_global_load_lds(
                (const __attribute__((address_space(1))) void*)ga,
                (__attribute__((address_space(3))) void*)&lda[(wave * (BMt / 4) + j * 8) * BK],
                16, 0, 0);
        }
#pragma unroll
        for (int j = 0; j < 4; ++j) {
            int r = wave * 32 + j * 8 + srow8;
            const u16* gb = B + (b_base + r) * (long)K + kk + sg * 8;
            __builtin_amdgcn_global_load_lds(
                (const __attribute__((address_space(1))) void*)gb,
                (__attribute__((address_space(3))) void*)&ldb[(wave * 32 + j * 8) * BK],
                16, 0, 0);
        }
        __syncthreads();
#pragma unroll
        for (int kh = 0; kh < 2; ++kh) {
            // chunk swizzle: k-half 1 flips bit2 of the chunk -> offset XOR 32 elems
            bf16x8 af[MI], bfr[4];
#pragma unroll
            for (int i = 0; i < MI; ++i) af[i]  = *(const bf16x8*)&lda[a_off[i] ^ (kh << 5)];
#pragma unroll
            for (int i = 0; i < 4; ++i) bfr[i] = *(const bf16x8*)&ldb[b_off[i] ^ (kh << 5)];
#pragma unroll
            for (int mi = 0; mi < MI; ++mi)
#pragma unroll
                for (int ni = 0; ni < 4; ++ni)
                    acc[mi][ni] = __builtin_amdgcn_mfma_f32_16x16x32_bf16(
                        af[mi], bfr[ni], acc[mi][ni], 0, 0, 0);
        }
        __syncthreads();
    }

    // epilogue: C/D layout col=lane&15, row=(lane>>4)*4+reg
    const long row0 = a_base + wm * WM;
    const long col0 = b_base + wn * 64;
#pragma unroll
    for (int mi = 0; mi < MI; ++mi) {
#pragma unroll
        for (int ni = 0; ni < 4; ++ni) {
            long col = col0 + ni * 16 + fr;
            float bv = bias[col];
            long rowb = row0 + mi * 16 + fq * 4;
#pragma unroll
            for (int rr = 0; rr < 4; ++rr) {
                float v = acc[mi][ni][rr] + bv;
                long idx = (rowb + rr) * (long)N + col;
                if (OUT_BF16) ((u16*)C)[idx] = f2bf(v);
                else          ((float*)C)[idx] = v;
            }
        }
    }
}

// ---------------- banded attention, query-pair version (unchanged from R2) ----------------
#define AQ 128
#define AW 16
#define AROWS (AQ + 2 * AW)   // 160
#define ASTR 70

__device__ __forceinline__ void unpack16(const u32* __restrict__ src, float* __restrict__ dst) {
#pragma unroll
    for (int dd = 0; dd < 8; ++dd) {
        u32 wv = src[dd];
        dst[2 * dd]     = bf2f((u16)(wv & 0xffffu));
        dst[2 * dd + 1] = bf2f((u16)(wv >> 16));
    }
}

__global__ __launch_bounds__(256)
void attn_kernel(const u16* __restrict__ qkv, const float* __restrict__ radius,
                 u16* __restrict__ out)
{
    __shared__ u16 ks[AROWS * ASTR];
    __shared__ u16 vs[AROWS * ASTR];

    const int tid = threadIdx.x;
    const int bid = blockIdx.x;
    const int qc = bid & 15;
    const int h  = (bid >> 4) & 7;
    const int b  = bid >> 7;
    const int q0 = qc * AQ;

    float rad = radius[h];
    float r = 16.0f / (1.0f + __expf(-rad));
    r = fmaxf(r, 1.0f);
    const int w = (int)floorf(r);       // 1..15

    for (int cid = tid; cid < AROWS * 4; cid += 256) {
        int row = cid >> 2;
        int ch  = cid & 3;
        int t = min(max(q0 - AW + row, 0), T_LEN - 1);
        const u16* gk = qkv + ((long)(b * T_LEN + t)) * QKV_N + D_MOD + h * HDIM + ch * 16;
        const u16* gv = gk + D_MOD;
        uint4 k0 = *(const uint4*)gk, k1 = *(const uint4*)(gk + 8);
        uint4 v0 = *(const uint4*)gv, v1 = *(const uint4*)(gv + 8);
        u32* kd = (u32*)&ks[row * ASTR + ch * 18];
        u32* vd = (u32*)&vs[row * ASTR + ch * 18];
        kd[0] = k0.x; kd[1] = k0.y; kd[2] = k0.z; kd[3] = k0.w;
        kd[4] = k1.x; kd[5] = k1.y; kd[6] = k1.z; kd[7] = k1.w;
        vd[0] = v0.x; vd[1] = v0.y; vd[2] = v0.z; vd[3] = v0.w;
        vd[4] = v1.x; vd[5] = v1.y; vd[6] = v1.z; vd[7] = v1.w;
    }

    const int p = tid >> 2;          // pair index 0..63
    const int g = tid & 3;           // dim group (16 dims)
    const int qA = q0 + 2 * p;
    const long rowA = (long)(b * T_LEN + qA);
    const long rowB = rowA + 1;

    float qregA[16], qregB[16];
    {
        const u16* gq = qkv + rowA * QKV_N + h * HDIM + g * 16;
        u32 wa[8], wb[8];
        uint4 t0 = *(const uint4*)gq,              t1 = *(const uint4*)(gq + 8);
        uint4 t2 = *(const uint4*)(gq + QKV_N),    t3 = *(const uint4*)(gq + QKV_N + 8);
        wa[0]=t0.x; wa[1]=t0.y; wa[2]=t0.z; wa[3]=t0.w; wa[4]=t1.x; wa[5]=t1.y; wa[6]=t1.z; wa[7]=t1.w;
        wb[0]=t2.x; wb[1]=t2.y; wb[2]=t2.z; wb[3]=t2.w; wb[4]=t3.x; wb[5]=t3.y; wb[6]=t3.z; wb[7]=t3.w;
#pragma unroll
        for (int j = 0; j < 8; ++j) {
            qregA[2 * j]     = bf2f((u16)(wa[j] & 0xffffu)) * 0.125f;
            qregA[2 * j + 1] = bf2f((u16)(wa[j] >> 16))     * 0.125f;
            qregB[2 * j]     = bf2f((u16)(wb[j] & 0xffffu)) * 0.125f;
            qregB[2 * j + 1] = bf2f((u16)(wb[j] >> 16))     * 0.125f;
        }
    }
    __syncthreads();

    float mA = -1e30f, lA = 0.0f, mB = -1e30f, lB = 0.0f;
    float accA[16], accB[16];
#pragma unroll
    for (int d = 0; d < 16; ++d) { accA[d] = 0.0f; accB[d] = 0.0f; }

    const int imax = 2 * w + 1;
    for (int i = 0; i <= imax; ++i) {
        int jrow = 2 * p - w + i;
        int j = q0 + jrow;
        int row = jrow + AW;
        float kf[16];
        unpack16((const u32*)&ks[row * ASTR + g * 18], kf);
        float sA = 0.0f, sB = 0.0f;
#pragma unroll
        for (int d = 0; d < 16; ++d) { sA += qregA[d] * kf[d]; sB += qregB[d] * kf[d]; }
        sA += __shfl_xor(sA, 1); sA += __shfl_xor(sA, 2);
        sB += __shfl_xor(sB, 1); sB += __shfl_xor(sB, 2);
        bool inb = ((unsigned)j) < (unsigned)T_LEN;
        bool vA = inb && (i < imax);
        bool vB = inb && (i > 0);
        float mnA = fmaxf(mA, vA ? sA : -1e30f);
        float scA = __expf(mA - mnA);
        float pA  = vA ? __expf(sA - mnA) : 0.0f;
        mA = mnA; lA = lA * scA + pA;
        float mnB = fmaxf(mB, vB ? sB : -1e30f);
        float scB = __expf(mB - mnB);
        float pB  = vB ? __expf(sB - mnB) : 0.0f;
        mB = mnB; lB = lB * scB + pB;
        float vf[16];
        unpack16((const u32*)&vs[row * ASTR + g * 18], vf);
#pragma unroll
        for (int d = 0; d < 16; ++d) {
            accA[d] = accA[d] * scA + pA * vf[d];
            accB[d] = accB[d] * scB + pB * vf[d];
        }
    }

    float invA = 1.0f / lA;
    float invB = 1.0f / lB;
    u32 oA[8], oB[8];
#pragma unroll
    for (int j2 = 0; j2 < 8; ++j2) {
        oA[j2] = (u32)f2bf(accA[2 * j2] * invA) | ((u32)f2bf(accA[2 * j2 + 1] * invA) << 16);
        oB[j2] = (u32)f2bf(accB[2 * j2] * invB) | ((u32)f2bf(accB[2 * j2 + 1] * invB) << 16);
    }
    u16* poA = out + rowA * D_MOD + h * HDIM + g * 16;
    u16* poB = out + rowB * D_MOD + h * HDIM + g * 16;
    *(uint4*)poA       = make_uint4(oA[0], oA[1], oA[2], oA[3]);
    *(uint4*)(poA + 8) = make_uint4(oA[4], oA[5], oA[6], oA[7]);
    *(uint4*)poB       = make_uint4(oB[0], oB[1], oB[2], oB[3]);
    *(uint4*)(poB + 8) = make_uint4(oB[4], oB[5], oB[6], oB[7]);
}

// ---------------- launch ----------------
extern "C" void kernel_launch(void* const* d_in, const int* in_sizes, int n_in,
                              void* d_out, int out_size, void* d_ws, size_t ws_size,
                              hipStream_t stream)
{
    (void)in_sizes; (void)n_in; (void)out_size; (void)ws_size;
    const float* x      = (const float*)d_in[0];
    const float* radius = (const float*)d_in[1];
    const float* w_in   = (const float*)d_in[2];
    const float* b_in   = (const float*)d_in[3];
    const float* w_out  = (const float*)d_in[4];
    const float* b_out  = (const float*)d_in[5];
    float* outp = (float*)d_out;

    char* ws = (char*)d_ws;
    u16* x_bf    = (u16*)ws;  ws += (size_t)M_ROWS * D_MOD * 2;
    u16* win_bf  = (u16*)ws;  ws += (size_t)QKV_N * D_MOD * 2;
    u16* wout_bf = (u16*)ws;  ws += (size_t)D_MOD * D_MOD * 2;
    u16* qkv_bf  = (u16*)ws;  ws += (size_t)M_ROWS * QKV_N * 2;
    u16* attn_bf = (u16*)ws;

    const int na = M_ROWS * D_MOD;        // 4194304
    const int nb = QKV_N * D_MOD;         // 786432
    const int nc = D_MOD * D_MOD;         // 262144
    cast3_kernel<<<(na + nb + nc) / 2048, 256, 0, stream>>>(
        x, na, w_in, nb, w_out, x_bf, win_bf, wout_bf);

    gemm_bt<true, 128><<<dim3(QKV_N / 128, M_ROWS / 128), 256, 0, stream>>>(
        x_bf, win_bf, b_in, qkv_bf, M_ROWS, QKV_N, D_MOD);
    attn_kernel<<<B_SZ * N_HEAD * (T_LEN / AQ), 256, 0, stream>>>(qkv_bf, radius, attn_bf);
    gemm_bt<false, 64><<<dim3(D_MOD / 128, M_ROWS / 64), 256, 0, stream>>>(
        attn_bf, wout_bf, b_out, outp, M_ROWS, D_MOD, D_MOD);
}